// Round 2
// baseline (7592.068 us; speedup 1.0000x reference)
//
#include <hip/hip_runtime.h>

typedef _Float16 f16;
typedef f16 f16x8 __attribute__((ext_vector_type(8)));
typedef float f32x4 __attribute__((ext_vector_type(4)));

#define MFMA16(a, b, c) __builtin_amdgcn_mfma_f32_16x16x32_f16(a, b, c, 0, 0, 0)

__device__ inline float fsig(float x) { return 1.f / (1.f + __expf(-x)); }
__device__ inline float ftanh(float x) {
    x = fminf(15.f, fmaxf(-15.f, x));
    float e = __expf(2.f * x);
    return (e - 1.f) / (e + 1.f);
}

// ---------------- one-time conversions ----------------
__global__ __launch_bounds__(256) void k_convert(
    const float* __restrict__ Wih, const float* __restrict__ Whh,
    const float* __restrict__ W1, const float* __restrict__ W2,
    const float* __restrict__ henc, const float* __restrict__ bih,
    const float* __restrict__ bhh,
    f16* __restrict__ wcat, f16* __restrict__ w1t, f16* __restrict__ w2a,
    f16* __restrict__ w2b, f16* __restrict__ h16, float* __restrict__ bsum)
{
    const long NW = 16777216, NT = 1048576, NA = 524288, NB = 524288,
               NH = 8388608, NS = 8192;
    const long TOT = NW + NT + NA + NB + NH + NS;
    for (long i = (long)blockIdx.x * 256 + threadIdx.x; i < TOT;
         i += (long)gridDim.x * 256) {
        if (i < NW) {
            long l = i >> 23;                  // / (4096*2048)
            long r = i & 8388607;
            int j = (int)(r >> 11), k = (int)(r & 2047);
            float val = (k < 1024) ? Wih[(l * 4096 + j) * 1024 + k]
                                   : Whh[(l * 4096 + j) * 1024 + (k - 1024)];
            wcat[i] = (f16)val;
        } else if (i < NW + NT) {
            long r = i - NW;
            int h = (int)(r >> 10), v = (int)(r & 1023);
            w1t[r] = (f16)W1[(long)v * 1024 + h];
        } else if (i < NW + NT + NA) {
            long r = i - NW - NT;
            int e = (int)(r >> 10), v = (int)(r & 1023);
            w2a[r] = (f16)W2[(long)e * 2048 + v];
        } else if (i < NW + NT + NA + NB) {
            long r = i - NW - NT - NA;
            int e = (int)(r >> 10), k = (int)(r & 1023);
            w2b[r] = (f16)W2[(long)e * 2048 + 1024 + k];
        } else if (i < NW + NT + NA + NB + NH) {
            long r = i - NW - NT - NA - NB;
            h16[r] = (f16)henc[r];
        } else {
            long r = i - NW - NT - NA - NB - NH;
            bsum[r] = bih[r] + bhh[r];
        }
    }
}

// ---------------- state init ----------------
__global__ __launch_bounds__(256) void k_init(
    const int* __restrict__ tgt, const float* __restrict__ emb,
    const float* __restrict__ oinit, const float* __restrict__ hinit,
    f16* __restrict__ A1_0, f16* __restrict__ A2_0, float* __restrict__ c01,
    unsigned* __restrict__ bar)
{
    int idx = blockIdx.x * 256 + threadIdx.x;   // 0 .. 393215
    if (idx == 0) *bar = 0u;
    if (idx < 131072) {                  // A1[0] = [x0 | o_init | h0_init]
        int m = idx >> 11, k = idx & 2047;
        float val;
        if (k < 512)       val = emb[(long)tgt[m] * 512 + k];
        else if (k < 1024) val = oinit[m * 512 + (k - 512)];
        else               val = hinit[m * 1024 + (k - 1024)];
        A1_0[idx] = (f16)val;
    } else if (idx < 262144) {           // A2[0] = [0 | h1_init]
        int r = idx - 131072;
        int m = r >> 11, k = r & 2047;
        A2_0[r] = (f16)((k < 1024) ? 0.f : hinit[(64 + m) * 1024 + (k - 1024)]);
    } else {                             // c = 0
        c01[idx - 262144] = 0.f;
    }
}

// ---------------- sb[b,s] = b1 . h_enc[b,s,:] ----------------
__global__ __launch_bounds__(256) void k_sb(
    const float* __restrict__ b1, const float* __restrict__ henc,
    float* __restrict__ sb)
{
    int bs = blockIdx.x * 256 + threadIdx.x;   // 0..8191
    const float* hr = henc + (long)bs * 1024;
    float a = 0.f;
    for (int k = 0; k < 1024; k += 4) {
        float4 h4 = *(const float4*)(hr + k);
        float4 b4 = *(const float4*)(b1 + k);
        a += h4.x * b4.x + h4.y * b4.y + h4.z * b4.z + h4.w * b4.w;
    }
    sb[bs] = a;
}

// ---------------- generic f16 GEMM: C[M,N] = A[M,1024] * B[N,1024]^T ----------------
__global__ __launch_bounds__(256) void k_gemm(
    const f16* __restrict__ A, const f16* __restrict__ Bm,
    f16* __restrict__ C, int N)
{
    int nb = N >> 7;
    int bm = blockIdx.x / nb, bn = blockIdx.x % nb;
    int tid = threadIdx.x, w = tid >> 6, lane = tid & 63;
    int quad = lane >> 4, nn = lane & 15;
    const f16* ap = A + (long)(bm * 64 + w * 16 + nn) * 1024 + quad * 8;
    const f16* bp = Bm + (long)(bn * 128 + nn) * 1024 + quad * 8;
    f32x4 acc[8] = {};
    for (int kk = 0; kk < 1024; kk += 32) {
        f16x8 av = *(const f16x8*)(ap + kk);
        #pragma unroll
        for (int t2 = 0; t2 < 8; ++t2) {
            f16x8 bv = *(const f16x8*)(bp + (long)t2 * 16 * 1024 + kk);
            acc[t2] = MFMA16(av, bv, acc[t2]);
        }
    }
    #pragma unroll
    for (int t2 = 0; t2 < 8; ++t2)
        #pragma unroll
        for (int r = 0; r < 4; ++r) {
            int m = bm * 64 + w * 16 + quad * 4 + r;
            int col = bn * 128 + t2 * 16 + nn;
            C[(long)m * N + col] = (f16)acc[t2][r];
        }
}

// ---------------- grid barrier (cooperative launch, 256 blocks) ----------------
__device__ __forceinline__ void gsync(unsigned* bar, unsigned target) {
    __syncthreads();
    if (threadIdx.x == 0) {
        __threadfence();
        __hip_atomic_fetch_add(bar, 1u, __ATOMIC_RELAXED, __HIP_MEMORY_SCOPE_AGENT);
        while (__hip_atomic_load(bar, __ATOMIC_RELAXED, __HIP_MEMORY_SCOPE_AGENT) < target)
            __builtin_amdgcn_s_sleep(1);
        __threadfence();
    }
    __syncthreads();
}

// ---------------- fused LSTM layer (per block: 4 units x 4 gates, splitK-8) ----------------
__device__ __forceinline__ void lstm_layer(
    const f16* __restrict__ A, const f16* __restrict__ W,
    const float* __restrict__ bsum, float* __restrict__ c,
    f16* __restrict__ hd0, f16* __restrict__ hd1, float* __restrict__ hfull,
    float* lds, int b, int tid)
{
    int w = tid >> 6, lane = tid & 63;
    int quad = lane >> 4, n = lane & 15;
    int g = n & 3, u = n >> 2;
    int j = g * 1024 + b * 4 + u;            // gate column (i,f,g,o blocks of 1024)
    const f16* ap = A + (long)n * 2048 + w * 256 + quad * 8;
    const f16* bp = W + (long)j * 2048 + w * 256 + quad * 8;
    f32x4 acc0 = {}, acc1 = {}, acc2 = {}, acc3 = {};
    #pragma unroll
    for (int kk = 0; kk < 256; kk += 32) {
        f16x8 bv = *(const f16x8*)(bp + kk);
        f16x8 a0 = *(const f16x8*)(ap + kk);
        f16x8 a1 = *(const f16x8*)(ap + 32768 + kk);
        f16x8 a2 = *(const f16x8*)(ap + 65536 + kk);
        f16x8 a3 = *(const f16x8*)(ap + 98304 + kk);
        acc0 = MFMA16(a0, bv, acc0);
        acc1 = MFMA16(a1, bv, acc1);
        acc2 = MFMA16(a2, bv, acc2);
        acc3 = MFMA16(a3, bv, acc3);
    }
    #pragma unroll
    for (int r = 0; r < 4; ++r) {
        int mb = quad * 4 + r;
        lds[(w * 64 + mb) * 17 + n]      = acc0[r];
        lds[(w * 64 + 16 + mb) * 17 + n] = acc1[r];
        lds[(w * 64 + 32 + mb) * 17 + n] = acc2[r];
        lds[(w * 64 + 48 + mb) * 17 + n] = acc3[r];
    }
    __syncthreads();
    if (tid < 256) {
        int m = tid >> 2, uu = tid & 3;
        float s0 = 0.f, s1 = 0.f, s2 = 0.f, s3 = 0.f;
        #pragma unroll
        for (int ww = 0; ww < 8; ++ww) {
            const float* p = lds + (ww * 64 + m) * 17 + uu * 4;
            s0 += p[0]; s1 += p[1]; s2 += p[2]; s3 += p[3];
        }
        int ug = b * 4 + uu;
        float iv = fsig(s0 + bsum[ug]);
        float fv = fsig(s1 + bsum[1024 + ug]);
        float gv = ftanh(s2 + bsum[2048 + ug]);
        float ov = fsig(s3 + bsum[3072 + ug]);
        float cold = c[m * 1024 + ug];
        float cn = fv * cold + iv * gv;
        float hn = ov * ftanh(cn);
        c[m * 1024 + ug] = cn;
        hd0[m * 2048 + ug] = (f16)hn;
        if (hd1) hd1[m * 2048 + ug] = (f16)hn;
        if (hfull) hfull[m * 1024 + ug] = hn;
    }
}

// ---------------- Z1 = h1(f16) @ w2b^T + b2 : [64][512], K=1024, 32 blocks ----------------
__device__ __forceinline__ void z1_gemm(
    const f16* __restrict__ A, const f16* __restrict__ Bw,
    const float* __restrict__ b2, float* __restrict__ Z1,
    float* lds, int bb, int tid)
{
    int w = tid >> 6, lane = tid & 63;
    int quad = lane >> 4, n = lane & 15;
    int j = bb * 16 + n;
    const f16* ap = A + (long)n * 2048 + w * 128 + quad * 8;
    const f16* bp = Bw + (long)j * 1024 + w * 128 + quad * 8;
    f32x4 acc0 = {}, acc1 = {}, acc2 = {}, acc3 = {};
    #pragma unroll
    for (int kk = 0; kk < 128; kk += 32) {
        f16x8 bv = *(const f16x8*)(bp + kk);
        f16x8 a0 = *(const f16x8*)(ap + kk);
        f16x8 a1 = *(const f16x8*)(ap + 32768 + kk);
        f16x8 a2 = *(const f16x8*)(ap + 65536 + kk);
        f16x8 a3 = *(const f16x8*)(ap + 98304 + kk);
        acc0 = MFMA16(a0, bv, acc0);
        acc1 = MFMA16(a1, bv, acc1);
        acc2 = MFMA16(a2, bv, acc2);
        acc3 = MFMA16(a3, bv, acc3);
    }
    #pragma unroll
    for (int r = 0; r < 4; ++r) {
        int mb = quad * 4 + r;
        lds[(w * 64 + mb) * 17 + n]      = acc0[r];
        lds[(w * 64 + 16 + mb) * 17 + n] = acc1[r];
        lds[(w * 64 + 32 + mb) * 17 + n] = acc2[r];
        lds[(w * 64 + 48 + mb) * 17 + n] = acc3[r];
    }
    __syncthreads();
    int m = tid >> 3, n0 = (tid & 7) * 2;
    float s0 = 0.f, s1 = 0.f;
    #pragma unroll
    for (int ww = 0; ww < 8; ++ww) {
        const float* p = lds + (ww * 64 + m) * 17 + n0;
        s0 += p[0]; s1 += p[1];
    }
    int e = bb * 16 + n0;
    Z1[m * 512 + e]     = s0 + b2[e];
    Z1[m * 512 + e + 1] = s1 + b2[e + 1];
}

// ---------------- persistent decoder: all 64 steps, 4 grid syncs per step ----------------
__global__ __launch_bounds__(512, 2) void k_persist(
    const f16* __restrict__ wcat, const float* __restrict__ bsum,
    float* __restrict__ c01, f16* __restrict__ A1, f16* __restrict__ A2,
    float* __restrict__ h1f, const f16* __restrict__ P16,
    const f16* __restrict__ Q216, const f16* __restrict__ w2b16,
    const float* __restrict__ sb, const float* __restrict__ b2,
    const int* __restrict__ tgt, const float* __restrict__ emb,
    float* __restrict__ out, float* __restrict__ Z1, unsigned* __restrict__ bar)
{
    __shared__ float lds[8704];
    int b = blockIdx.x, tid = threadIdx.x;
    unsigned epoch = 0;
    for (int t = 0; t < 64; ++t) {
        int cur = t & 1, nxt = cur ^ 1;
        f16* A1c = A1 + cur * 131072; f16* A1n = A1 + nxt * 131072;
        f16* A2c = A2 + cur * 131072; f16* A2n = A2 + nxt * 131072;

        // S1: layer 0 — h0 -> A2c[:,0:1024] and A1n[:,1024:2048]
        lstm_layer(A1c, wcat, bsum, c01, A2c, A1n + 1024, (float*)nullptr, lds, b, tid);
        gsync(bar, (++epoch) * 256u);

        // S2: layer 1 — h1 -> A2n[:,1024:2048] (f16) and h1f (fp32)
        lstm_layer(A2c, wcat + 8388608, bsum + 4096, c01 + 65536,
                   A2n + 1024, (f16*)nullptr, h1f, lds, b, tid);
        gsync(bar, (++epoch) * 256u);

        // S3: attn scores/softmax/Z2 (blocks 0..63) | Z1 MFMA (64..95) | x-gather (96..159)
        if (b < 64) {
            int m = b;
            ((float2*)lds)[tid] = ((const float2*)(h1f + m * 1024))[tid];
            __syncthreads();
            int s = tid >> 2, ph = tid & 3;
            const f16* pr = P16 + ((long)(m * 128 + s)) * 1024 + ph * 256;
            const float* hb = lds + ph * 256;
            float a0 = 0.f;
            #pragma unroll 4
            for (int k = 0; k < 256; k += 8) {
                f16x8 pv = *(const f16x8*)(pr + k);
                #pragma unroll
                for (int j2 = 0; j2 < 8; ++j2) a0 += hb[k + j2] * (float)pv[j2];
            }
            lds[1024 + tid] = a0;                    // spart[s][ph] = spart[tid]
            __syncthreads();
            if (tid < 128) {
                float sc = lds[1024 + tid * 4] + lds[1025 + tid * 4]
                         + lds[1026 + tid * 4] + lds[1027 + tid * 4]
                         + sb[m * 128 + tid];
                lds[1536 + tid] = sc;
            }
            __syncthreads();
            if (tid < 64) {
                float v = fmaxf(lds[1536 + tid], lds[1600 + tid]);
                #pragma unroll
                for (int off = 32; off; off >>= 1) v = fmaxf(v, __shfl_down(v, off));
                if (tid == 0) lds[1700] = v;
            }
            __syncthreads();
            float mx = lds[1700];
            if (tid < 128) lds[1536 + tid] = __expf(lds[1536 + tid] - mx);
            __syncthreads();
            if (tid < 64) {
                float v = lds[1536 + tid] + lds[1600 + tid];
                #pragma unroll
                for (int off = 32; off; off >>= 1) v += __shfl_down(v, off);
                if (tid == 0) lds[1701] = 1.f / v;
            }
            __syncthreads();
            float inv = lds[1701];
            float z2 = 0.f;
            const f16* q2 = Q216 + (long)m * 65536 + tid;
            #pragma unroll 8
            for (int s2 = 0; s2 < 128; ++s2)
                z2 += lds[1536 + s2] * (float)q2[(long)s2 * 512];
            lds[2048 + tid] = z2 * inv;              // Z2 stays in LDS across sync
        } else if (b < 96) {
            z1_gemm(A2n + 1024, w2b16, b2, Z1, lds, b - 64, tid);
        } else if (b < 160 && t < 63) {
            int m = b - 96;
            int row = tgt[(t + 1) * 64 + m];
            A1n[m * 2048 + tid] = (f16)emb[(long)row * 512 + tid];
        }
        gsync(bar, (++epoch) * 256u);

        // S4: o = tanh(Z1 + Z2) -> d_out and A1n[:,512:1024]
        if (b < 64) {
            float o = ftanh(Z1[b * 512 + tid] + lds[2048 + tid]);
            out[((long)b * 64 + t) * 512 + tid] = o;
            A1n[b * 2048 + 512 + tid] = (f16)o;
        }
        gsync(bar, (++epoch) * 256u);
    }
}

extern "C" void kernel_launch(void* const* d_in, const int* in_sizes, int n_in,
                              void* d_out, int out_size, void* d_ws, size_t ws_size,
                              hipStream_t stream)
{
    const int*   tgt   = (const int*)d_in[0];
    const float* henc  = (const float*)d_in[1];
    const float* emb   = (const float*)d_in[2];
    const float* oinit = (const float*)d_in[3];
    const float* hinit = (const float*)d_in[4];
    const float* Wih   = (const float*)d_in[5];
    const float* Whh   = (const float*)d_in[6];
    const float* bih   = (const float*)d_in[7];
    const float* bhh   = (const float*)d_in[8];
    const float* W1    = (const float*)d_in[9];
    const float* b1    = (const float*)d_in[10];
    const float* W2    = (const float*)d_in[11];
    const float* b2    = (const float*)d_in[12];
    float* out = (float*)d_out;

    char* ws = (char*)d_ws;
    f16*      wcat  = (f16*)(ws + 0);              // [2][4096][2048]   32 MB
    f16*      P16   = (f16*)(ws + 33554432);       // [8192][1024]      16 MB
    f16*      Q216  = (f16*)(ws + 50331648);       // [8192][512]        8 MB
    f16*      h16   = (f16*)(ws + 58720256);       // [8192][1024]      16 MB
    f16*      w1t   = (f16*)(ws + 75497472);       // [1024][1024]       2 MB
    f16*      w2a   = (f16*)(ws + 77594624);       // [512][1024]        1 MB
    f16*      w2b16 = (f16*)(ws + 78643200);       // [512][1024]        1 MB
    f16*      A1    = (f16*)(ws + 79691776);       // [2][64][2048]    512 KB
    f16*      A2    = (f16*)(ws + 80216064);       // [2][64][2048]    512 KB
    float*    h1f   = (float*)(ws + 80740352);     // [64][1024]       256 KB
    float*    c01   = (float*)(ws + 81002496);     // [2][64][1024]    512 KB
    float*    sb    = (float*)(ws + 81526784);     // [64][128]         32 KB
    float*    bsum  = (float*)(ws + 81559552);     // [2][4096]         32 KB
    unsigned* bar   = (unsigned*)(ws + 81592320);  // barrier counter
    float*    Z1    = (float*)(ws + 81592448);     // [64][512]        128 KB

    hipLaunchKernelGGL(k_convert, dim3(4096), dim3(256), 0, stream,
                       Wih, Whh, W1, W2, henc, bih, bhh,
                       wcat, w1t, w2a, w2b16, h16, bsum);
    hipLaunchKernelGGL(k_init, dim3(1536), dim3(256), 0, stream,
                       tgt, emb, oinit, hinit, A1, A2, c01, bar);
    hipLaunchKernelGGL(k_sb, dim3(32), dim3(256), 0, stream, b1, henc, sb);
    hipLaunchKernelGGL(k_gemm, dim3(128 * 8), dim3(256), 0, stream, h16, w1t, P16, 1024);
    hipLaunchKernelGGL(k_gemm, dim3(128 * 4), dim3(256), 0, stream, h16, w2a, Q216, 512);

    void* args[] = { &wcat, &bsum, &c01, &A1, &A2, &h1f, &P16, &Q216, &w2b16,
                     &sb, &b2, &tgt, &emb, &out, &Z1, &bar };
    hipLaunchCooperativeKernel((const void*)k_persist, dim3(256), dim3(512),
                               args, 0, stream);
}

// Round 3
// 3945.182 us; speedup vs baseline: 1.9244x; 1.9244x over previous
//
#include <hip/hip_runtime.h>

typedef _Float16 f16;
typedef f16 f16x8 __attribute__((ext_vector_type(8)));
typedef f16 f16x2 __attribute__((ext_vector_type(2)));
typedef float f32x4 __attribute__((ext_vector_type(4)));
typedef unsigned long long u64;

#define MFMA16(a, b, c) __builtin_amdgcn_mfma_f32_16x16x32_f16(a, b, c, 0, 0, 0)

__device__ inline float fsig(float x) { return 1.f / (1.f + __expf(-x)); }
__device__ inline float ftanh(float x) {
    x = fminf(15.f, fmaxf(-15.f, x));
    float e = __expf(2.f * x);
    return (e - 1.f) / (e + 1.f);
}

// 8-byte agent-scope (LLC-coherent, L2-bypassing) store/load
__device__ __forceinline__ void bstore8(void* p, u64 v) {
    __hip_atomic_store((u64*)p, v, __ATOMIC_RELAXED, __HIP_MEMORY_SCOPE_AGENT);
}
__device__ __forceinline__ float bload_f32(const float* p) {
    return __hip_atomic_load((float*)p, __ATOMIC_RELAXED, __HIP_MEMORY_SCOPE_AGENT);
}

// ---------------- one-time conversions ----------------
__global__ __launch_bounds__(256) void k_convert(
    const float* __restrict__ Wih, const float* __restrict__ Whh,
    const float* __restrict__ W1, const float* __restrict__ W2,
    const float* __restrict__ bih, const float* __restrict__ bhh,
    f16* __restrict__ wcat, f16* __restrict__ w1c, f16* __restrict__ w2a,
    f16* __restrict__ w2b, float* __restrict__ bsum)
{
    const long NW = 16777216, NT = 1048576, NA = 524288, NB = 524288, NS = 8192;
    const long TOT = NW + NT + NA + NB + NS;
    for (long i = (long)blockIdx.x * 256 + threadIdx.x; i < TOT;
         i += (long)gridDim.x * 256) {
        if (i < NW) {
            long l = i >> 23;
            long r = i & 8388607;
            int j = (int)(r >> 11), k = (int)(r & 2047);
            float val = (k < 1024) ? Wih[(l * 4096 + j) * 1024 + k]
                                   : Whh[(l * 4096 + j) * 1024 + (k - 1024)];
            wcat[i] = (f16)val;
        } else if (i < NW + NT) {
            long r = i - NW;
            int h = (int)(r >> 10), v = (int)(r & 1023);
            w1c[r] = (f16)W1[(long)v * 1024 + h];          // w1c[h][v] = W1^T
        } else if (i < NW + NT + NA) {
            long r = i - NW - NT;
            int e = (int)(r >> 10), v = (int)(r & 1023);
            w2a[r] = (f16)W2[(long)e * 2048 + v];
        } else if (i < NW + NT + NA + NB) {
            long r = i - NW - NT - NA;
            int e = (int)(r >> 10), k = (int)(r & 1023);
            w2b[r] = (f16)W2[(long)e * 2048 + 1024 + k];
        } else {
            long r = i - NW - NT - NA - NB;
            bsum[r] = bih[r] + bhh[r];
        }
    }
}

// ---------------- state init (slot 0 of rotated buffers) ----------------
__global__ __launch_bounds__(256) void k_init(
    const int* __restrict__ tgt, const float* __restrict__ emb,
    const float* __restrict__ oinit, const float* __restrict__ hinit,
    f16* __restrict__ X0, f16* __restrict__ O0, f16* __restrict__ H00,
    f16* __restrict__ H10, float* __restrict__ c01, unsigned* __restrict__ bar)
{
    int idx = blockIdx.x * 256 + threadIdx.x;   // 0 .. 327679
    if (idx == 0) *bar = 0u;
    if (idx < 32768) {
        int m = idx >> 9, k = idx & 511;
        X0[idx] = (f16)emb[(long)tgt[m] * 512 + k];
    } else if (idx < 65536) {
        int r = idx - 32768;
        O0[r] = (f16)oinit[r];
    } else if (idx < 131072) {
        int r = idx - 65536;
        H00[r] = (f16)hinit[r];                       // layer 0
    } else if (idx < 196608) {
        int r = idx - 131072;
        H10[r] = (f16)hinit[65536 + r];               // layer 1
    } else if (idx < 327680) {
        c01[idx - 196608] = 0.f;
    }
}

// ---------------- sb[b,s] = b1 . h_enc[b,s,:] ----------------
__global__ __launch_bounds__(256) void k_sb(
    const float* __restrict__ b1, const float* __restrict__ henc,
    float* __restrict__ sb)
{
    int bs = blockIdx.x * 256 + threadIdx.x;
    const float* hr = henc + (long)bs * 1024;
    float a = 0.f;
    for (int k = 0; k < 1024; k += 4) {
        float4 h4 = *(const float4*)(hr + k);
        float4 b4 = *(const float4*)(b1 + k);
        a += h4.x * b4.x + h4.y * b4.y + h4.z * b4.z + h4.w * b4.w;
    }
    sb[bs] = a;
}

// ---------------- GEMM: C[M,N](f16) = Afp32[M,1024] * B16[N,1024]^T ----------------
__global__ __launch_bounds__(256) void k_gemm_f32a(
    const float* __restrict__ A, const f16* __restrict__ Bm,
    f16* __restrict__ C, int N)
{
    int nb = N >> 7;
    int bm = blockIdx.x / nb, bn = blockIdx.x % nb;
    int tid = threadIdx.x, w = tid >> 6, lane = tid & 63;
    int quad = lane >> 4, nn = lane & 15;
    const float* ap = A + (long)(bm * 64 + w * 16 + nn) * 1024 + quad * 8;
    const f16* bp = Bm + (long)(bn * 128 + nn) * 1024 + quad * 8;
    f32x4 acc[8] = {};
    for (int kk = 0; kk < 1024; kk += 32) {
        float4 x0 = *(const float4*)(ap + kk);
        float4 x1 = *(const float4*)(ap + kk + 4);
        f16x8 av = { (f16)x0.x, (f16)x0.y, (f16)x0.z, (f16)x0.w,
                     (f16)x1.x, (f16)x1.y, (f16)x1.z, (f16)x1.w };
        #pragma unroll
        for (int t2 = 0; t2 < 8; ++t2) {
            f16x8 bv = *(const f16x8*)(bp + (long)t2 * 16 * 1024 + kk);
            acc[t2] = MFMA16(av, bv, acc[t2]);
        }
    }
    #pragma unroll
    for (int t2 = 0; t2 < 8; ++t2)
        #pragma unroll
        for (int r = 0; r < 4; ++r) {
            int m = bm * 64 + w * 16 + quad * 4 + r;
            int col = bn * 128 + t2 * 16 + nn;
            C[(long)m * N + col] = (f16)acc[t2][r];
        }
}

// ---------------- fence-free grid barrier ----------------
__device__ __forceinline__ void gsync(unsigned* bar, unsigned target) {
    asm volatile("s_waitcnt vmcnt(0) lgkmcnt(0)" ::: "memory");
    __syncthreads();
    if (threadIdx.x == 0) {
        __hip_atomic_fetch_add(bar, 1u, __ATOMIC_RELAXED, __HIP_MEMORY_SCOPE_AGENT);
        while (__hip_atomic_load(bar, __ATOMIC_RELAXED, __HIP_MEMORY_SCOPE_AGENT) < target)
            __builtin_amdgcn_s_sleep(4);
    }
    __syncthreads();
    asm volatile("" ::: "memory");
}

// ---------------- LSTM layer core: block owns 4 units x 4 gates, splitK-8 ----------------
__device__ __forceinline__ void lstm_core(
    const f16* base, int rst, const f16* __restrict__ W,
    const float* __restrict__ bs_, float* __restrict__ c_,
    f16* __restrict__ dest, float* lds, int b, int tid)
{
    int w = tid >> 6, lane = tid & 63, quad = lane >> 4, n = lane & 15;
    int g = n & 3, u = n >> 2;
    int j = g * 1024 + b * 4 + u;
    const f16* ap = base + (long)n * rst + quad * 8;
    const f16* bp = W + (long)j * 2048 + w * 256 + quad * 8;
    f32x4 acc0 = {}, acc1 = {}, acc2 = {}, acc3 = {};
    #pragma unroll
    for (int kk = 0; kk < 256; kk += 32) {
        f16x8 bv = *(const f16x8*)(bp + kk);
        f16x8 a0 = *(const f16x8*)(ap + kk);
        f16x8 a1 = *(const f16x8*)(ap + (long)16 * rst + kk);
        f16x8 a2 = *(const f16x8*)(ap + (long)32 * rst + kk);
        f16x8 a3 = *(const f16x8*)(ap + (long)48 * rst + kk);
        acc0 = MFMA16(a0, bv, acc0);
        acc1 = MFMA16(a1, bv, acc1);
        acc2 = MFMA16(a2, bv, acc2);
        acc3 = MFMA16(a3, bv, acc3);
    }
    #pragma unroll
    for (int r = 0; r < 4; ++r) {
        int mb = quad * 4 + r;
        lds[(w * 64 + mb) * 17 + n]      = acc0[r];
        lds[(w * 64 + 16 + mb) * 17 + n] = acc1[r];
        lds[(w * 64 + 32 + mb) * 17 + n] = acc2[r];
        lds[(w * 64 + 48 + mb) * 17 + n] = acc3[r];
    }
    __syncthreads();
    if (tid < 256) {
        int m = tid >> 2, uu = tid & 3;
        float s0 = 0.f, s1 = 0.f, s2 = 0.f, s3 = 0.f;
        #pragma unroll
        for (int ww = 0; ww < 8; ++ww) {
            const float* p = lds + (ww * 64 + m) * 17 + uu * 4;
            s0 += p[0]; s1 += p[1]; s2 += p[2]; s3 += p[3];
        }
        int ug = b * 4 + uu;
        float iv = fsig(s0 + bs_[ug]);
        float fv = fsig(s1 + bs_[1024 + ug]);
        float gv = ftanh(s2 + bs_[2048 + ug]);
        float ov = fsig(s3 + bs_[3072 + ug]);
        float cold = c_[m * 1024 + ug];          // block-private: normal cached
        float cn = fv * cold + iv * gv;
        float hn = ov * ftanh(cn);
        c_[m * 1024 + ug] = cn;
        lds[8704 + m * 4 + uu] = hn;
    }
    __syncthreads();
    if (tid < 64) {
        union { f16 h[4]; u64 u; } pk;
        #pragma unroll
        for (int uu = 0; uu < 4; ++uu) pk.h[uu] = (f16)lds[8704 + tid * 4 + uu];
        bstore8(dest + (long)tid * 1024 + b * 4, pk.u);
    }
}

// ---------------- persistent decoder ----------------
__global__ __launch_bounds__(512, 1) void k_persist(
    const f16* __restrict__ wcat, const float* __restrict__ bsum,
    float* __restrict__ c01,
    f16* __restrict__ Xrot, f16* __restrict__ Orot,
    f16* __restrict__ H0rot, f16* __restrict__ H1rot,
    const f16* __restrict__ P16, const f16* __restrict__ Q216,
    const f16* __restrict__ w2b, const float* __restrict__ sb,
    const float* __restrict__ b2, const int* __restrict__ tgt,
    const float* __restrict__ emb, float* __restrict__ out,
    float* __restrict__ Z1f, unsigned* __restrict__ bar)
{
    __shared__ float lds[8960];
    int b = blockIdx.x, tid = threadIdx.x;
    unsigned epoch = 0;
    for (int t = 0; t < 64; ++t) {
        int rs0 = t % 48, rs1 = (t + 1) % 48;
        const f16* Xc = Xrot + rs0 * 32768;
        const f16* Oc = Orot + rs0 * 32768;
        const f16* H0c = H0rot + (long)rs0 * 65536;
        f16* H0n = H0rot + (long)rs1 * 65536;
        const f16* H1c = H1rot + (long)rs0 * 65536;
        f16* H1n = H1rot + (long)rs1 * 65536;

        // ---- S1: layer 0, K = [x(512) | o(512) | h0prev(1024)] ----
        {
            int w = tid >> 6;
            const f16* base; int rst;
            if (w < 2)      { base = Xc + w * 256;        rst = 512; }
            else if (w < 4) { base = Oc + (w - 2) * 256;  rst = 512; }
            else            { base = H0c + (w - 4) * 256; rst = 1024; }
            lstm_core(base, rst, wcat, bsum, c01, H0n, lds, b, tid);
        }
        gsync(bar, (++epoch) * 256u);

        // ---- S2: layer 1, K = [h0(1024) | h1prev(1024)] ----
        {
            int w = tid >> 6;
            const f16* base = (w < 4) ? (H0n + w * 256) : (H1c + (w - 4) * 256);
            lstm_core(base, 1024, wcat + 8388608, bsum + 4096, c01 + 65536,
                      H1n, lds, b, tid);
        }
        gsync(bar, (++epoch) * 256u);

        // ---- S3: attn (0..63) | Z1 MFMA (64..95) | x-gather (96..159) ----
        if (b < 64) {
            int m = b;
            unsigned* hh = (unsigned*)lds;
            if (tid < 128) {
                uint4 hv = *(const uint4*)(H1n + (long)m * 1024 + tid * 8);
                hh[tid * 4 + 0] = hv.x; hh[tid * 4 + 1] = hv.y;
                hh[tid * 4 + 2] = hv.z; hh[tid * 4 + 3] = hv.w;
            }
            __syncthreads();
            int s = tid >> 2, ph = tid & 3;
            const uint4* pr = (const uint4*)(P16 + ((long)(m * 128 + s)) * 1024 + ph * 256);
            float a0 = 0.f;
            #pragma unroll 8
            for (int i = 0; i < 32; ++i) {
                uint4 pv = pr[i];
                a0 = __builtin_amdgcn_fdot2(__builtin_bit_cast(f16x2, pv.x),
                        __builtin_bit_cast(f16x2, hh[ph * 128 + i * 4 + 0]), a0, false);
                a0 = __builtin_amdgcn_fdot2(__builtin_bit_cast(f16x2, pv.y),
                        __builtin_bit_cast(f16x2, hh[ph * 128 + i * 4 + 1]), a0, false);
                a0 = __builtin_amdgcn_fdot2(__builtin_bit_cast(f16x2, pv.z),
                        __builtin_bit_cast(f16x2, hh[ph * 128 + i * 4 + 2]), a0, false);
                a0 = __builtin_amdgcn_fdot2(__builtin_bit_cast(f16x2, pv.w),
                        __builtin_bit_cast(f16x2, hh[ph * 128 + i * 4 + 3]), a0, false);
            }
            lds[512 + tid] = a0;
            __syncthreads();
            if (tid < 128) {
                float sc = lds[512 + tid * 4] + lds[513 + tid * 4]
                         + lds[514 + tid * 4] + lds[515 + tid * 4] + sb[m * 128 + tid];
                lds[1024 + tid] = sc;
            }
            __syncthreads();
            if (tid < 64) {
                float v = fmaxf(lds[1024 + tid], lds[1088 + tid]);
                #pragma unroll
                for (int off = 32; off; off >>= 1) v = fmaxf(v, __shfl_down(v, off));
                if (tid == 0) lds[1152] = v;
            }
            __syncthreads();
            if (tid < 128) lds[1024 + tid] = __expf(lds[1024 + tid] - lds[1152]);
            __syncthreads();
            if (tid < 64) {
                float v = lds[1024 + tid] + lds[1088 + tid];
                #pragma unroll
                for (int off = 32; off; off >>= 1) v += __shfl_down(v, off);
                if (tid == 0) lds[1153] = 1.f / v;
            }
            __syncthreads();
            float inv = lds[1153];
            float z2 = 0.f;
            const f16* q2 = Q216 + (long)m * 65536 + tid;
            #pragma unroll 8
            for (int s2 = 0; s2 < 128; ++s2)
                z2 += lds[1024 + s2] * (float)q2[(long)s2 * 512];
            lds[1280 + tid] = z2 * inv;              // Z2 survives in LDS across gsync
        } else if (b < 96) {
            int bb = b - 64;
            int w = tid >> 6, lane = tid & 63, quad = lane >> 4, n = lane & 15;
            int j = bb * 16 + n;
            const f16* ap = H1n + (long)n * 1024 + w * 128 + quad * 8;
            const f16* bp = w2b + (long)j * 1024 + w * 128 + quad * 8;
            f32x4 acc0 = {}, acc1 = {}, acc2 = {}, acc3 = {};
            #pragma unroll
            for (int kk = 0; kk < 128; kk += 32) {
                f16x8 bv = *(const f16x8*)(bp + kk);
                f16x8 a0 = *(const f16x8*)(ap + kk);
                f16x8 a1 = *(const f16x8*)(ap + 16384 + kk);
                f16x8 a2 = *(const f16x8*)(ap + 32768 + kk);
                f16x8 a3 = *(const f16x8*)(ap + 49152 + kk);
                acc0 = MFMA16(a0, bv, acc0);
                acc1 = MFMA16(a1, bv, acc1);
                acc2 = MFMA16(a2, bv, acc2);
                acc3 = MFMA16(a3, bv, acc3);
            }
            #pragma unroll
            for (int r = 0; r < 4; ++r) {
                int mb = quad * 4 + r;
                lds[(w * 64 + mb) * 17 + n]      = acc0[r];
                lds[(w * 64 + 16 + mb) * 17 + n] = acc1[r];
                lds[(w * 64 + 32 + mb) * 17 + n] = acc2[r];
                lds[(w * 64 + 48 + mb) * 17 + n] = acc3[r];
            }
            __syncthreads();
            int m = tid >> 3, n0 = (tid & 7) * 2;
            float s0 = 0.f, s1 = 0.f;
            #pragma unroll
            for (int ww = 0; ww < 8; ++ww) {
                const float* p = lds + (ww * 64 + m) * 17 + n0;
                s0 += p[0]; s1 += p[1];
            }
            int e = bb * 16 + n0;
            union { float f[2]; u64 u; } pk;
            pk.f[0] = s0 + b2[e]; pk.f[1] = s1 + b2[e + 1];
            bstore8(Z1f + (long)m * 512 + e, pk.u);
        } else if (b < 160) {
            if (t < 63 && tid < 128) {
                int m = b - 96;
                int row = tgt[(t + 1) * 64 + m];
                float4 ev = *(const float4*)(emb + (long)row * 512 + tid * 4);
                union { f16 h[4]; u64 u; } pk;
                pk.h[0] = (f16)ev.x; pk.h[1] = (f16)ev.y;
                pk.h[2] = (f16)ev.z; pk.h[3] = (f16)ev.w;
                bstore8(Xrot + (long)rs1 * 32768 + m * 512 + tid * 4, pk.u);
            }
        }
        gsync(bar, (++epoch) * 256u);

        // ---- S4: o = tanh(Z1 + Z2) ----
        if (b < 64) {
            float z1 = bload_f32(Z1f + (long)b * 512 + tid);
            float o = ftanh(z1 + lds[1280 + tid]);
            out[((long)b * 64 + t) * 512 + tid] = o;
            lds[1792 + tid] = o;
            __syncthreads();
            if (tid < 128) {
                union { f16 h[4]; u64 u; } pk;
                #pragma unroll
                for (int i = 0; i < 4; ++i) pk.h[i] = (f16)lds[1792 + tid * 4 + i];
                bstore8(Orot + (long)rs1 * 32768 + b * 512 + tid * 4, pk.u);
            }
        }
        gsync(bar, (++epoch) * 256u);
    }
}

extern "C" void kernel_launch(void* const* d_in, const int* in_sizes, int n_in,
                              void* d_out, int out_size, void* d_ws, size_t ws_size,
                              hipStream_t stream)
{
    const int*   tgt   = (const int*)d_in[0];
    const float* henc  = (const float*)d_in[1];
    const float* emb   = (const float*)d_in[2];
    const float* oinit = (const float*)d_in[3];
    const float* hinit = (const float*)d_in[4];
    const float* Wih   = (const float*)d_in[5];
    const float* Whh   = (const float*)d_in[6];
    const float* bih   = (const float*)d_in[7];
    const float* bhh   = (const float*)d_in[8];
    const float* W1    = (const float*)d_in[9];
    const float* b1    = (const float*)d_in[10];
    const float* W2    = (const float*)d_in[11];
    const float* b2    = (const float*)d_in[12];
    float* out = (float*)d_out;

    char* ws = (char*)d_ws;
    f16*      wcat  = (f16*)(ws + 0);              // 32 MB
    f16*      P16   = (f16*)(ws + 33554432);       // 16 MB
    f16*      Q216  = (f16*)(ws + 50331648);       //  8 MB
    f16*      w2b   = (f16*)(ws + 58720256);       //  1 MB
    f16*      H0rot = (f16*)(ws + 59768832);       // 48 x 128 KB
    f16*      H1rot = (f16*)(ws + 66060288);       // 48 x 128 KB
    f16*      Xrot  = (f16*)(ws + 72351744);       // 48 x 64 KB
    f16*      Orot  = (f16*)(ws + 75497472);       // 48 x 64 KB
    float*    c01   = (float*)(ws + 78643200);     // 512 KB
    float*    Z1f   = (float*)(ws + 79167488);     // 128 KB
    float*    bsum  = (float*)(ws + 79298560);     //  32 KB
    float*    sb    = (float*)(ws + 79331328);     //  32 KB
    unsigned* bar   = (unsigned*)(ws + 79364096);
    // setup-only aliases inside rotation slots >= 1 (overwritten only after consumed)
    f16*      w1c   = Xrot + 32768;                // Xrot slots 1..32  (2 MB)
    f16*      w2a   = Orot + 32768;                // Orot slots 1..16  (1 MB)

    hipLaunchKernelGGL(k_convert, dim3(4096), dim3(256), 0, stream,
                       Wih, Whh, W1, W2, bih, bhh, wcat, w1c, w2a, w2b, bsum);
    hipLaunchKernelGGL(k_init, dim3(1280), dim3(256), 0, stream,
                       tgt, emb, oinit, hinit, Xrot, Orot, H0rot, H1rot, c01, bar);
    hipLaunchKernelGGL(k_sb, dim3(32), dim3(256), 0, stream, b1, henc, sb);
    hipLaunchKernelGGL(k_gemm_f32a, dim3(128 * 8), dim3(256), 0, stream,
                       henc, w1c, P16, 1024);
    hipLaunchKernelGGL(k_gemm_f32a, dim3(128 * 4), dim3(256), 0, stream,
                       henc, w2a, Q216, 512);

    void* args[] = { &wcat, &bsum, &c01, &Xrot, &Orot, &H0rot, &H1rot, &P16,
                     &Q216, &w2b, &sb, &b2, &tgt, &emb, &out, &Z1f, &bar };
    hipLaunchCooperativeKernel((const void*)k_persist, dim3(256), dim3(512),
                               args, 0, stream);
}

// Round 4
// 3630.976 us; speedup vs baseline: 2.0909x; 1.0865x over previous
//
#include <hip/hip_runtime.h>

typedef _Float16 f16;
typedef f16 f16x8 __attribute__((ext_vector_type(8)));
typedef f16 f16x2 __attribute__((ext_vector_type(2)));
typedef float f32x4 __attribute__((ext_vector_type(4)));
typedef unsigned long long u64;

#define MFMA16(a, b, c) __builtin_amdgcn_mfma_f32_16x16x32_f16(a, b, c, 0, 0, 0)

__device__ inline float fsig(float x) { return 1.f / (1.f + __expf(-x)); }
__device__ inline float ftanh(float x) {
    x = fminf(15.f, fmaxf(-15.f, x));
    float e = __expf(2.f * x);
    return (e - 1.f) / (e + 1.f);
}

// LLC-coherent (L2-bypassing) relaxed atomic ld/st
__device__ __forceinline__ void bstore8(void* p, u64 v) {
    __hip_atomic_store((u64*)p, v, __ATOMIC_RELAXED, __HIP_MEMORY_SCOPE_AGENT);
}
__device__ __forceinline__ void bstore4(float* p, float v) {
    __hip_atomic_store(p, v, __ATOMIC_RELAXED, __HIP_MEMORY_SCOPE_AGENT);
}
__device__ __forceinline__ float bload_f32(const float* p) {
    return __hip_atomic_load((float*)p, __ATOMIC_RELAXED, __HIP_MEMORY_SCOPE_AGENT);
}

// ---------------- one-time conversions + embedding pre-gather ----------------
__global__ __launch_bounds__(256) void k_convert(
    const float* __restrict__ Wih, const float* __restrict__ Whh,
    const float* __restrict__ W1, const float* __restrict__ W2,
    const float* __restrict__ bih, const float* __restrict__ bhh,
    const int* __restrict__ tgt, const float* __restrict__ emb,
    f16* __restrict__ wcat, f16* __restrict__ w1c, f16* __restrict__ w2a,
    f16* __restrict__ w2b, float* __restrict__ bsum, f16* __restrict__ Xall)
{
    const long NW = 16777216, NT = 1048576, NA = 524288, NB = 524288,
               NS = 8192, NX = 2097152;
    const long TOT = NW + NT + NA + NB + NS + NX;
    for (long i = (long)blockIdx.x * 256 + threadIdx.x; i < TOT;
         i += (long)gridDim.x * 256) {
        if (i < NW) {
            long l = i >> 23;
            long r = i & 8388607;
            int j = (int)(r >> 11), k = (int)(r & 2047);
            float val = (k < 1024) ? Wih[(l * 4096 + j) * 1024 + k]
                                   : Whh[(l * 4096 + j) * 1024 + (k - 1024)];
            wcat[i] = (f16)val;
        } else if (i < NW + NT) {
            long r = i - NW;
            int h = (int)(r >> 10), v = (int)(r & 1023);
            w1c[r] = (f16)W1[(long)v * 1024 + h];
        } else if (i < NW + NT + NA) {
            long r = i - NW - NT;
            int e = (int)(r >> 10), v = (int)(r & 1023);
            w2a[r] = (f16)W2[(long)e * 2048 + v];
        } else if (i < NW + NT + NA + NB) {
            long r = i - NW - NT - NA;
            int e = (int)(r >> 10), k = (int)(r & 1023);
            w2b[r] = (f16)W2[(long)e * 2048 + 1024 + k];
        } else if (i < NW + NT + NA + NB + NS) {
            long r = i - NW - NT - NA - NB;
            bsum[r] = bih[r] + bhh[r];
        } else {
            long r = i - NW - NT - NA - NB - NS;
            int t = (int)(r >> 15), mm = (int)((r >> 9) & 63), k = (int)(r & 511);
            Xall[r] = (f16)emb[(long)tgt[t * 64 + mm] * 512 + k];
        }
    }
}

// ---------------- state init ----------------
__global__ __launch_bounds__(256) void k_init(
    const float* __restrict__ oinit, const float* __restrict__ hinit,
    f16* __restrict__ O0, f16* __restrict__ H00, f16* __restrict__ H10,
    float* __restrict__ c01, unsigned* __restrict__ cnt, unsigned* __restrict__ bar)
{
    int idx = blockIdx.x * 256 + threadIdx.x;
    if (idx < 32768) {
        O0[idx] = (f16)oinit[idx];
    } else if (idx < 98304) {
        int r = idx - 32768;
        H00[r] = (f16)hinit[r];
    } else if (idx < 163840) {
        int r = idx - 98304;
        H10[r] = (f16)hinit[65536 + r];
    } else if (idx < 294912) {
        c01[idx - 163840] = 0.f;
    } else if (idx < 294976) {
        cnt[idx - 294912] = 0u;
    } else if (idx == 294976) {
        *bar = 0u;
    }
}

// ---------------- sb[b,s] = b1 . h_enc[b,s,:] ----------------
__global__ __launch_bounds__(256) void k_sb(
    const float* __restrict__ b1, const float* __restrict__ henc,
    float* __restrict__ sb)
{
    int bs = blockIdx.x * 256 + threadIdx.x;
    const float* hr = henc + (long)bs * 1024;
    float a = 0.f;
    for (int k = 0; k < 1024; k += 4) {
        float4 h4 = *(const float4*)(hr + k);
        float4 b4 = *(const float4*)(b1 + k);
        a += h4.x * b4.x + h4.y * b4.y + h4.z * b4.z + h4.w * b4.w;
    }
    sb[bs] = a;
}

// ---------------- GEMM: C[M,N](f16) = Afp32[M,1024] * B16[N,1024]^T ----------------
__global__ __launch_bounds__(256) void k_gemm_f32a(
    const float* __restrict__ A, const f16* __restrict__ Bm,
    f16* __restrict__ C, int N)
{
    int nb = N >> 7;
    int bm = blockIdx.x / nb, bn = blockIdx.x % nb;
    int tid = threadIdx.x, w = tid >> 6, lane = tid & 63;
    int quad = lane >> 4, nn = lane & 15;
    const float* ap = A + (long)(bm * 64 + w * 16 + nn) * 1024 + quad * 8;
    const f16* bp = Bm + (long)(bn * 128 + nn) * 1024 + quad * 8;
    f32x4 acc[8] = {};
    for (int kk = 0; kk < 1024; kk += 32) {
        float4 x0 = *(const float4*)(ap + kk);
        float4 x1 = *(const float4*)(ap + kk + 4);
        f16x8 av = { (f16)x0.x, (f16)x0.y, (f16)x0.z, (f16)x0.w,
                     (f16)x1.x, (f16)x1.y, (f16)x1.z, (f16)x1.w };
        #pragma unroll
        for (int t2 = 0; t2 < 8; ++t2) {
            f16x8 bv = *(const f16x8*)(bp + (long)t2 * 16 * 1024 + kk);
            acc[t2] = MFMA16(av, bv, acc[t2]);
        }
    }
    #pragma unroll
    for (int t2 = 0; t2 < 8; ++t2)
        #pragma unroll
        for (int r = 0; r < 4; ++r) {
            int m = bm * 64 + w * 16 + quad * 4 + r;
            int col = bn * 128 + t2 * 16 + nn;
            C[(long)m * N + col] = (f16)acc[t2][r];
        }
}

// ---------------- fence-free grid barrier ----------------
__device__ __forceinline__ void gsync(unsigned* bar, unsigned target) {
    asm volatile("s_waitcnt vmcnt(0) lgkmcnt(0)" ::: "memory");
    __syncthreads();
    if (threadIdx.x == 0) {
        __hip_atomic_fetch_add(bar, 1u, __ATOMIC_RELAXED, __HIP_MEMORY_SCOPE_AGENT);
        while (__hip_atomic_load(bar, __ATOMIC_RELAXED, __HIP_MEMORY_SCOPE_AGENT) < target)
            __builtin_amdgcn_s_sleep(4);
    }
    __syncthreads();
    asm volatile("" ::: "memory");
}

// ---------------- LSTM layer core: weights from registers ----------------
__device__ __forceinline__ void lstm_core(
    const f16* base, int rst, const f16x8* wreg,
    const float* __restrict__ bs_, float* __restrict__ c_,
    f16* __restrict__ dest, float* lds, int b, int tid)
{
    int w = tid >> 6, lane = tid & 63, quad = lane >> 4, n = lane & 15;
    const f16* ap = base + (long)n * rst + quad * 8;
    f32x4 acc0 = {}, acc1 = {}, acc2 = {}, acc3 = {};
    #pragma unroll
    for (int kk = 0; kk < 8; ++kk) {
        f16x8 bv = wreg[kk];
        f16x8 a0 = *(const f16x8*)(ap + kk * 32);
        f16x8 a1 = *(const f16x8*)(ap + (long)16 * rst + kk * 32);
        f16x8 a2 = *(const f16x8*)(ap + (long)32 * rst + kk * 32);
        f16x8 a3 = *(const f16x8*)(ap + (long)48 * rst + kk * 32);
        acc0 = MFMA16(a0, bv, acc0);
        acc1 = MFMA16(a1, bv, acc1);
        acc2 = MFMA16(a2, bv, acc2);
        acc3 = MFMA16(a3, bv, acc3);
    }
    #pragma unroll
    for (int r = 0; r < 4; ++r) {
        int mb = quad * 4 + r;
        lds[(w * 64 + mb) * 17 + n]      = acc0[r];
        lds[(w * 64 + 16 + mb) * 17 + n] = acc1[r];
        lds[(w * 64 + 32 + mb) * 17 + n] = acc2[r];
        lds[(w * 64 + 48 + mb) * 17 + n] = acc3[r];
    }
    __syncthreads();
    if (tid < 256) {
        int m = tid >> 2, uu = tid & 3;
        float s0 = 0.f, s1 = 0.f, s2 = 0.f, s3 = 0.f;
        #pragma unroll
        for (int ww = 0; ww < 8; ++ww) {
            const float* p = lds + (ww * 64 + m) * 17 + uu * 4;
            s0 += p[0]; s1 += p[1]; s2 += p[2]; s3 += p[3];
        }
        int ug = b * 4 + uu;
        float iv = fsig(s0 + bs_[ug]);
        float fv = fsig(s1 + bs_[1024 + ug]);
        float gv = ftanh(s2 + bs_[2048 + ug]);
        float ov = fsig(s3 + bs_[3072 + ug]);
        float cold = c_[m * 1024 + ug];
        float cn = fv * cold + iv * gv;
        float hn = ov * ftanh(cn);
        c_[m * 1024 + ug] = cn;
        lds[8704 + m * 4 + uu] = hn;
    }
    __syncthreads();
    if (tid < 64) {
        union { f16 h[4]; u64 u; } pk;
        #pragma unroll
        for (int uu = 0; uu < 4; ++uu) pk.h[uu] = (f16)lds[8704 + tid * 4 + uu];
        bstore8(dest + (long)tid * 1024 + b * 4, pk.u);
    }
}

// ---------------- Z1 core (blocks 64..95): weights from registers ----------------
__device__ __forceinline__ void z1_core(
    const f16* __restrict__ H1n, const f16x8* wz,
    const float* __restrict__ b2, float* __restrict__ Z1f,
    float* lds, int bb, int tid)
{
    int w = tid >> 6, lane = tid & 63, quad = lane >> 4, n = lane & 15;
    const f16* ap = H1n + (long)n * 1024 + w * 128 + quad * 8;
    f32x4 acc0 = {}, acc1 = {}, acc2 = {}, acc3 = {};
    #pragma unroll
    for (int kk = 0; kk < 4; ++kk) {
        f16x8 bv = wz[kk];
        f16x8 a0 = *(const f16x8*)(ap + kk * 32);
        f16x8 a1 = *(const f16x8*)(ap + 16384 + kk * 32);
        f16x8 a2 = *(const f16x8*)(ap + 32768 + kk * 32);
        f16x8 a3 = *(const f16x8*)(ap + 49152 + kk * 32);
        acc0 = MFMA16(a0, bv, acc0);
        acc1 = MFMA16(a1, bv, acc1);
        acc2 = MFMA16(a2, bv, acc2);
        acc3 = MFMA16(a3, bv, acc3);
    }
    #pragma unroll
    for (int r = 0; r < 4; ++r) {
        int mb = quad * 4 + r;
        lds[(w * 64 + mb) * 17 + n]      = acc0[r];
        lds[(w * 64 + 16 + mb) * 17 + n] = acc1[r];
        lds[(w * 64 + 32 + mb) * 17 + n] = acc2[r];
        lds[(w * 64 + 48 + mb) * 17 + n] = acc3[r];
    }
    __syncthreads();
    int m = tid >> 3, n0 = (tid & 7) * 2;
    float s0 = 0.f, s1 = 0.f;
    #pragma unroll
    for (int ww = 0; ww < 8; ++ww) {
        const float* p = lds + (ww * 64 + m) * 17 + n0;
        s0 += p[0]; s1 += p[1];
    }
    int e = bb * 16 + n0;
    union { float f[2]; u64 u; } pk;
    pk.f[0] = s0 + b2[e]; pk.f[1] = s1 + b2[e + 1];
    bstore8(Z1f + (long)m * 512 + e, pk.u);
}

// ---------------- persistent decoder ----------------
__global__ __launch_bounds__(512, 2) void k_persist(
    const f16* __restrict__ wcat, const float* __restrict__ bsum,
    float* __restrict__ c01, const f16* __restrict__ Xall,
    f16* __restrict__ Orot, f16* __restrict__ H0rot, f16* __restrict__ H1rot,
    const f16* __restrict__ P16, const f16* __restrict__ Q216,
    const f16* __restrict__ w2b, const float* __restrict__ sb,
    const float* __restrict__ b2, float* __restrict__ out,
    float* __restrict__ Z1f, float* __restrict__ Z2p, float* __restrict__ Sc,
    unsigned* __restrict__ cnt, unsigned* __restrict__ bar)
{
    extern __shared__ float smem[];
    float* scr = smem;                    // 8960 floats scratch
    f16* Pl  = (f16*)(smem + 8960);       // 32768 f16: P[m][sq*32+j][k]
    f16* Q2l = Pl + 32768;                // 16384 f16: Q2[m][sq*32+j][v]

    int b = blockIdx.x, tid = threadIdx.x;
    int m = b >> 2, sq = b & 3;
    int wv = tid >> 6, lane = tid & 63, quad = lane >> 4, nn = lane & 15;

    // -------- prologue: pin weights in VGPRs, P/Q2 slices in LDS --------
    f16x8 w0[8], w1[8];
    {
        int j0 = (nn & 3) * 1024 + b * 4 + (nn >> 2);
        const f16* wp = wcat + (long)j0 * 2048 + wv * 256 + quad * 8;
        #pragma unroll
        for (int kk = 0; kk < 8; ++kk) {
            w0[kk] = *(const f16x8*)(wp + kk * 32);
            w1[kk] = *(const f16x8*)(wp + 8388608 + kk * 32);
        }
    }
    f16x8 wz[4];
    if (b >= 64 && b < 96) {
        int j = (b - 64) * 16 + nn;
        const f16* zp = w2b + (long)j * 1024 + wv * 128 + quad * 8;
        #pragma unroll
        for (int kk = 0; kk < 4; ++kk) wz[kk] = *(const f16x8*)(zp + kk * 32);
    }
    {
        const uint4* gp = (const uint4*)(P16 + ((long)(m * 128 + sq * 32)) * 1024);
        #pragma unroll
        for (int i = 0; i < 8; ++i) ((uint4*)Pl)[i * 512 + tid] = gp[i * 512 + tid];
        const uint4* gq = (const uint4*)(Q216 + ((long)(m * 128 + sq * 32)) * 512);
        #pragma unroll
        for (int i = 0; i < 4; ++i) ((uint4*)Q2l)[i * 512 + tid] = gq[i * 512 + tid];
    }
    __syncthreads();

    unsigned epoch = 0;
    for (int t = 0; t < 64; ++t) {
        int rs0 = t % 48, rs1 = (t + 1) % 48;
        const f16* Xc = Xall + (long)t * 32768;
        const f16* Oc = Orot + (long)rs0 * 32768;
        const f16* H0c = H0rot + (long)rs0 * 65536;
        f16* H0n = H0rot + (long)rs1 * 65536;
        const f16* H1c = H1rot + (long)rs0 * 65536;
        f16* H1n = H1rot + (long)rs1 * 65536;

        // ---- S1: layer 0, K = [x(512) | o(512) | h0prev(1024)] ----
        {
            const f16* base; int rst;
            if (wv < 2)      { base = Xc + wv * 256;        rst = 512; }
            else if (wv < 4) { base = Oc + (wv - 2) * 256;  rst = 512; }
            else             { base = H0c + (wv - 4) * 256; rst = 1024; }
            lstm_core(base, rst, w0, bsum, c01, H0n, scr, b, tid);
        }
        gsync(bar, (++epoch) * 256u);

        // ---- S2: layer 1, K = [h0(1024) | h1prev(1024)] ----
        {
            const f16* base = (wv < 4) ? (H0n + wv * 256) : (H1c + (wv - 4) * 256);
            lstm_core(base, 1024, w1, bsum + 4096, c01 + 65536, H1n, scr, b, tid);
        }
        gsync(bar, (++epoch) * 256u);

        // ---- S3: scores (all blocks, 32 s each) + Z1 (blocks 64..95) ----
        {
            f16* h1l = (f16*)scr;
            if (tid < 128)
                ((uint4*)h1l)[tid] = *(const uint4*)(H1n + (long)m * 1024 + tid * 8);
            __syncthreads();
            int sl = tid >> 4, kc = tid & 15;
            const f16* prow = Pl + sl * 1024;
            float a0 = 0.f;
            #pragma unroll
            for (int i = 0; i < 8; ++i) {
                int ch = (i * 16 + kc) * 8;
                f16x8 pv = *(const f16x8*)(prow + ch);
                f16x8 hv = *(const f16x8*)(h1l + ch);
                #pragma unroll
                for (int p2 = 0; p2 < 4; ++p2) {
                    f16x2 pa = { pv[p2 * 2], pv[p2 * 2 + 1] };
                    f16x2 ha = { hv[p2 * 2], hv[p2 * 2 + 1] };
                    a0 = __builtin_amdgcn_fdot2(pa, ha, a0, false);
                }
            }
            #pragma unroll
            for (int off = 8; off; off >>= 1) a0 += __shfl_xor(a0, off, 16);
            if (kc == 0)
                bstore4(Sc + m * 128 + sq * 32 + sl, a0 + sb[m * 128 + sq * 32 + sl]);
            __syncthreads();
            if (b >= 64 && b < 96)
                z1_core(H1n, wz, b2, Z1f, scr, b - 64, tid);
        }
        gsync(bar, (++epoch) * 256u);

        // ---- S4: softmax + Z2 partial + winner finish ----
        {
            if (tid < 128) scr[tid] = bload_f32(Sc + m * 128 + tid);
            __syncthreads();
            if (tid < 64) {
                float v = fmaxf(scr[tid], scr[64 + tid]);
                #pragma unroll
                for (int off = 32; off; off >>= 1) v = fmaxf(v, __shfl_down(v, off));
                if (tid == 0) scr[128] = v;
            }
            __syncthreads();
            if (tid < 128) scr[tid] = __expf(scr[tid] - scr[128]);
            __syncthreads();
            if (tid < 64) {
                float v = scr[tid] + scr[64 + tid];
                #pragma unroll
                for (int off = 32; off; off >>= 1) v += __shfl_down(v, off);
                if (tid == 0) scr[129] = 1.f / v;
            }
            __syncthreads();
            float inv = scr[129];
            float zp = 0.f;
            #pragma unroll 8
            for (int jy = 0; jy < 32; ++jy)
                zp += scr[sq * 32 + jy] * (float)Q2l[jy * 512 + tid];
            bstore4(Z2p + ((m * 4 + sq) << 9) + tid, zp * inv);
            asm volatile("s_waitcnt vmcnt(0)" ::: "memory");
            __syncthreads();
            if (tid == 0) {
                unsigned old = __hip_atomic_fetch_add(cnt + m, 1u, __ATOMIC_RELAXED,
                                                      __HIP_MEMORY_SCOPE_AGENT);
                scr[130] = (old == (unsigned)(4 * t + 3)) ? 1.f : 0.f;
            }
            __syncthreads();
            if (scr[130] != 0.f) {
                float z = bload_f32(Z1f + (m << 9) + tid);
                #pragma unroll
                for (int q = 0; q < 4; ++q)
                    z += bload_f32(Z2p + ((m * 4 + q) << 9) + tid);
                float o = ftanh(z);
                out[((long)m * 64 + t) * 512 + tid] = o;
                f16* ob = (f16*)(scr + 192);
                ob[tid] = (f16)o;
                __syncthreads();
                if (tid < 128) {
                    union { f16 h[4]; u64 u; } pk;
                    #pragma unroll
                    for (int i = 0; i < 4; ++i) pk.h[i] = ob[tid * 4 + i];
                    bstore8(Orot + (long)rs1 * 32768 + m * 512 + tid * 4, pk.u);
                }
            }
        }
        gsync(bar, (++epoch) * 256u);
    }
}

extern "C" void kernel_launch(void* const* d_in, const int* in_sizes, int n_in,
                              void* d_out, int out_size, void* d_ws, size_t ws_size,
                              hipStream_t stream)
{
    const int*   tgt   = (const int*)d_in[0];
    const float* henc  = (const float*)d_in[1];
    const float* emb   = (const float*)d_in[2];
    const float* oinit = (const float*)d_in[3];
    const float* hinit = (const float*)d_in[4];
    const float* Wih   = (const float*)d_in[5];
    const float* Whh   = (const float*)d_in[6];
    const float* bih   = (const float*)d_in[7];
    const float* bhh   = (const float*)d_in[8];
    const float* W1    = (const float*)d_in[9];
    const float* b1    = (const float*)d_in[10];
    const float* W2    = (const float*)d_in[11];
    const float* b2    = (const float*)d_in[12];
    float* out = (float*)d_out;

    char* ws = (char*)d_ws;
    f16*      wcat  = (f16*)(ws + 0);              // 32 MB
    f16*      P16   = (f16*)(ws + 33554432);       // 16 MB
    f16*      Q216  = (f16*)(ws + 50331648);       //  8 MB
    f16*      w2b   = (f16*)(ws + 58720256);       //  1 MB
    f16*      w1c   = (f16*)(ws + 59768832);       //  2 MB
    f16*      w2a   = (f16*)(ws + 61865984);       //  1 MB
    f16*      Xall  = (f16*)(ws + 62914560);       //  4 MB  [64][64][512]
    f16*      H0rot = (f16*)(ws + 67108864);       //  6 MB  48 slots
    f16*      H1rot = (f16*)(ws + 73400320);       //  6 MB
    f16*      Orot  = (f16*)(ws + 79691776);       //  3 MB
    float*    c01   = (float*)(ws + 82837504);     // 512 KB
    float*    Z1f   = (float*)(ws + 83361792);     // 128 KB
    float*    Z2p   = (float*)(ws + 83492864);     // 512 KB
    float*    Sc    = (float*)(ws + 84017152);     //  32 KB
    float*    bsum  = (float*)(ws + 84049920);     //  32 KB
    float*    sb    = (float*)(ws + 84082688);     //  32 KB
    unsigned* cnt   = (unsigned*)(ws + 84115456);  // 256 B
    unsigned* bar   = (unsigned*)(ws + 84115712);

    hipLaunchKernelGGL(k_convert, dim3(4096), dim3(256), 0, stream,
                       Wih, Whh, W1, W2, bih, bhh, tgt, emb,
                       wcat, w1c, w2a, w2b, bsum, Xall);
    hipLaunchKernelGGL(k_init, dim3(1153), dim3(256), 0, stream,
                       oinit, hinit, Orot, H0rot, H1rot, c01, cnt, bar);
    hipLaunchKernelGGL(k_sb, dim3(32), dim3(256), 0, stream, b1, henc, sb);
    hipLaunchKernelGGL(k_gemm_f32a, dim3(128 * 8), dim3(256), 0, stream,
                       henc, w1c, P16, 1024);
    hipLaunchKernelGGL(k_gemm_f32a, dim3(128 * 4), dim3(256), 0, stream,
                       henc, w2a, Q216, 512);

    static const unsigned LDS_BYTES = 8960 * 4 + 32768 * 2 + 16384 * 2; // 134144
    hipFuncSetAttribute((const void*)k_persist,
                        hipFuncAttributeMaxDynamicSharedMemorySize, LDS_BYTES);
    void* args[] = { &wcat, &bsum, &c01, &Xall, &Orot, &H0rot, &H1rot, &P16,
                     &Q216, &w2b, &sb, &b2, &out, &Z1f, &Z2p, &Sc, &cnt, &bar };
    hipLaunchCooperativeKernel((const void*)k_persist, dim3(256), dim3(512),
                               args, LDS_BYTES, stream);
}

// Round 5
// 2452.000 us; speedup vs baseline: 3.0963x; 1.4808x over previous
//
#include <hip/hip_runtime.h>

typedef _Float16 f16;
typedef f16 f16x8 __attribute__((ext_vector_type(8)));
typedef f16 f16x2 __attribute__((ext_vector_type(2)));
typedef float f32x4 __attribute__((ext_vector_type(4)));
typedef unsigned long long u64;

#define MFMA16(a, b, c) __builtin_amdgcn_mfma_f32_16x16x32_f16(a, b, c, 0, 0, 0)
#define ROT 16

__device__ inline float fsig(float x) { return 1.f / (1.f + __expf(-x)); }
__device__ inline float ftanh(float x) {
    x = fminf(15.f, fmaxf(-15.f, x));
    float e = __expf(2.f * x);
    return (e - 1.f) / (e + 1.f);
}

// LLC-coherent (L2-bypassing) relaxed atomic ld/st
__device__ __forceinline__ void bstore8(void* p, u64 v) {
    __hip_atomic_store((u64*)p, v, __ATOMIC_RELAXED, __HIP_MEMORY_SCOPE_AGENT);
}
__device__ __forceinline__ void bstore4(float* p, float v) {
    __hip_atomic_store(p, v, __ATOMIC_RELAXED, __HIP_MEMORY_SCOPE_AGENT);
}
__device__ __forceinline__ float bload_f32(const float* p) {
    return __hip_atomic_load((float*)p, __ATOMIC_RELAXED, __HIP_MEMORY_SCOPE_AGENT);
}

// ---------------- one-time conversions + embedding pre-gather ----------------
__global__ __launch_bounds__(256) void k_convert(
    const float* __restrict__ Wih, const float* __restrict__ Whh,
    const float* __restrict__ W1, const float* __restrict__ W2,
    const float* __restrict__ bih, const float* __restrict__ bhh,
    const int* __restrict__ tgt, const float* __restrict__ emb,
    const float* __restrict__ henc,
    f16* __restrict__ wcat, f16* __restrict__ w1c, f16* __restrict__ w2a,
    f16* __restrict__ w2b, float* __restrict__ bsum, f16* __restrict__ Xall,
    f16* __restrict__ h16)
{
    const long NW = 16777216, NT = 1048576, NA = 524288, NB = 524288,
               NS = 8192, NX = 2097152, NH = 8388608;
    const long TOT = NW + NT + NA + NB + NS + NX + NH;
    for (long i = (long)blockIdx.x * 256 + threadIdx.x; i < TOT;
         i += (long)gridDim.x * 256) {
        if (i < NW) {
            long l = i >> 23;
            long r = i & 8388607;
            int j = (int)(r >> 11), k = (int)(r & 2047);
            float val = (k < 1024) ? Wih[(l * 4096 + j) * 1024 + k]
                                   : Whh[(l * 4096 + j) * 1024 + (k - 1024)];
            wcat[i] = (f16)val;
        } else if (i < NW + NT) {
            long r = i - NW;
            int h = (int)(r >> 10), v = (int)(r & 1023);
            w1c[r] = (f16)W1[(long)v * 1024 + h];
        } else if (i < NW + NT + NA) {
            long r = i - NW - NT;
            int e = (int)(r >> 10), v = (int)(r & 1023);
            w2a[r] = (f16)W2[(long)e * 2048 + v];
        } else if (i < NW + NT + NA + NB) {
            long r = i - NW - NT - NA;
            int e = (int)(r >> 10), k = (int)(r & 1023);
            w2b[r] = (f16)W2[(long)e * 2048 + 1024 + k];
        } else if (i < NW + NT + NA + NB + NS) {
            long r = i - NW - NT - NA - NB;
            bsum[r] = bih[r] + bhh[r];
        } else if (i < NW + NT + NA + NB + NS + NX) {
            long r = i - NW - NT - NA - NB - NS;
            int t = (int)(r >> 15), mm = (int)((r >> 9) & 63), k = (int)(r & 511);
            Xall[r] = (f16)emb[(long)tgt[t * 64 + mm] * 512 + k];
        } else {
            long r = i - NW - NT - NA - NB - NS - NX;
            h16[r] = (f16)henc[r];
        }
    }
}

// ---------------- state init ----------------
__global__ __launch_bounds__(256) void k_init(
    const float* __restrict__ oinit, const float* __restrict__ hinit,
    f16* __restrict__ O0, f16* __restrict__ H00, f16* __restrict__ H10,
    float* __restrict__ c01, unsigned* __restrict__ sync)
{
    int idx = blockIdx.x * 256 + threadIdx.x;
    if (idx < 32768) {
        O0[idx] = (f16)oinit[idx];
    } else if (idx < 98304) {
        H00[idx - 32768] = (f16)hinit[idx - 32768];
    } else if (idx < 163840) {
        H10[idx - 98304] = (f16)hinit[65536 + (idx - 98304)];
    } else if (idx < 294912) {
        c01[idx - 163840] = 0.f;
    } else if (idx < 297984) {
        sync[idx - 294912] = 0u;    // arr[256] | rel[256] | mst pad | cnt[2048]
    }
}

// ---------------- sb[b,s] = b1 . h_enc[b,s,:] ----------------
__global__ __launch_bounds__(256) void k_sb(
    const float* __restrict__ b1, const float* __restrict__ henc,
    float* __restrict__ sb)
{
    int bs = blockIdx.x * 256 + threadIdx.x;
    const float* hr = henc + (long)bs * 1024;
    float a = 0.f;
    for (int k = 0; k < 1024; k += 4) {
        float4 h4 = *(const float4*)(hr + k);
        float4 b4 = *(const float4*)(b1 + k);
        a += h4.x * b4.x + h4.y * b4.y + h4.z * b4.z + h4.w * b4.w;
    }
    sb[bs] = a;
}

// ---------------- GEMM: C[M,N](f16) = A16[M,1024] * B16[N,1024]^T ----------------
__global__ __launch_bounds__(256) void k_gemm(
    const f16* __restrict__ A, const f16* __restrict__ Bm,
    f16* __restrict__ C, int N)
{
    int nb = N >> 7;
    int bm = blockIdx.x / nb, bn = blockIdx.x % nb;
    int tid = threadIdx.x, w = tid >> 6, lane = tid & 63;
    int quad = lane >> 4, nn = lane & 15;
    const f16* ap = A + (long)(bm * 64 + w * 16 + nn) * 1024 + quad * 8;
    const f16* bp = Bm + (long)(bn * 128 + nn) * 1024 + quad * 8;
    f32x4 acc[8] = {};
    for (int kk = 0; kk < 1024; kk += 32) {
        f16x8 av = *(const f16x8*)(ap + kk);
        #pragma unroll
        for (int t2 = 0; t2 < 8; ++t2) {
            f16x8 bv = *(const f16x8*)(bp + (long)t2 * 16 * 1024 + kk);
            acc[t2] = MFMA16(av, bv, acc[t2]);
        }
    }
    #pragma unroll
    for (int t2 = 0; t2 < 8; ++t2)
        #pragma unroll
        for (int r = 0; r < 4; ++r) {
            int m = bm * 64 + w * 16 + quad * 4 + r;
            int col = bn * 128 + t2 * 16 + nn;
            C[(long)m * N + col] = (f16)acc[t2][r];
        }
}

// ---------------- hierarchical fence-free grid barrier ----------------
// sync layout (u32): arr = sync + 32*g, rel = sync + 256 + 32*g, mst = sync + 512
__device__ __forceinline__ void gsync(unsigned* sync, unsigned e) {
    asm volatile("s_waitcnt vmcnt(0) lgkmcnt(0)" ::: "memory");
    __syncthreads();
    if (threadIdx.x == 0) {
        int g = blockIdx.x & 7;
        unsigned* arr = sync + 32 * g;
        unsigned* rel = sync + 256 + 32 * g;
        unsigned* mst = sync + 512;
        unsigned old = __hip_atomic_fetch_add(arr, 1u, __ATOMIC_RELAXED,
                                              __HIP_MEMORY_SCOPE_AGENT);
        if (old == e * 32u - 1u) {
            unsigned old2 = __hip_atomic_fetch_add(mst, 1u, __ATOMIC_RELAXED,
                                                   __HIP_MEMORY_SCOPE_AGENT);
            if (old2 == e * 8u - 1u) {
                #pragma unroll
                for (int g2 = 0; g2 < 8; ++g2)
                    __hip_atomic_store(sync + 256 + 32 * g2, e, __ATOMIC_RELAXED,
                                       __HIP_MEMORY_SCOPE_AGENT);
            }
        }
        while (__hip_atomic_fetch_add(rel, 0u, __ATOMIC_RELAXED,
                                      __HIP_MEMORY_SCOPE_AGENT) < e)
            __builtin_amdgcn_s_sleep(2);
    }
    __syncthreads();
    asm volatile("" ::: "memory");
}

// ---------------- LSTM layer core: weights pinned in VGPRs ----------------
__device__ __forceinline__ void lstm_core(
    const f16* base, int rst, const f16x8* wreg,
    const float* __restrict__ bs_, float* __restrict__ c_,
    f16* __restrict__ dest, float* lds, int b, int tid)
{
    int w = tid >> 6, lane = tid & 63, quad = lane >> 4, n = lane & 15;
    const f16* ap = base + (long)n * rst + quad * 8;
    f32x4 acc0 = {}, acc1 = {}, acc2 = {}, acc3 = {};
    #pragma unroll
    for (int kk = 0; kk < 8; ++kk) {
        f16x8 bv = wreg[kk];
        f16x8 a0 = *(const f16x8*)(ap + kk * 32);
        f16x8 a1 = *(const f16x8*)(ap + (long)16 * rst + kk * 32);
        f16x8 a2 = *(const f16x8*)(ap + (long)32 * rst + kk * 32);
        f16x8 a3 = *(const f16x8*)(ap + (long)48 * rst + kk * 32);
        acc0 = MFMA16(a0, bv, acc0);
        acc1 = MFMA16(a1, bv, acc1);
        acc2 = MFMA16(a2, bv, acc2);
        acc3 = MFMA16(a3, bv, acc3);
    }
    #pragma unroll
    for (int r = 0; r < 4; ++r) {
        int mb = quad * 4 + r;
        lds[(w * 64 + mb) * 17 + n]      = acc0[r];
        lds[(w * 64 + 16 + mb) * 17 + n] = acc1[r];
        lds[(w * 64 + 32 + mb) * 17 + n] = acc2[r];
        lds[(w * 64 + 48 + mb) * 17 + n] = acc3[r];
    }
    __syncthreads();
    if (tid < 256) {
        int m = tid >> 2, uu = tid & 3;
        float s0 = 0.f, s1 = 0.f, s2 = 0.f, s3 = 0.f;
        #pragma unroll
        for (int ww = 0; ww < 8; ++ww) {
            const float* p = lds + (ww * 64 + m) * 17 + uu * 4;
            s0 += p[0]; s1 += p[1]; s2 += p[2]; s3 += p[3];
        }
        int ug = b * 4 + uu;
        float iv = fsig(s0 + bs_[ug]);
        float fv = fsig(s1 + bs_[1024 + ug]);
        float gv = ftanh(s2 + bs_[2048 + ug]);
        float ov = fsig(s3 + bs_[3072 + ug]);
        float cold = c_[m * 1024 + ug];
        float cn = fv * cold + iv * gv;
        float hn = ov * ftanh(cn);
        c_[m * 1024 + ug] = cn;
        lds[8704 + m * 4 + uu] = hn;
    }
    __syncthreads();
    if (tid < 64) {
        union { f16 h[4]; u64 u; } pk;
        #pragma unroll
        for (int uu = 0; uu < 4; ++uu) pk.h[uu] = (f16)lds[8704 + tid * 4 + uu];
        bstore8(dest + (long)tid * 1024 + b * 4, pk.u);
    }
}

// ---------------- Z1 half-K core (blocks 64..127) ----------------
__device__ __forceinline__ void z1_core(
    const f16* __restrict__ H1n, const f16x8* wz, const float* __restrict__ b2,
    float* __restrict__ Z1f, int bb, int khalf, float* lds, int tid)
{
    int w = tid >> 6, lane = tid & 63, quad = lane >> 4, n = lane & 15;
    const f16* ap = H1n + (long)n * 1024 + khalf * 512 + w * 64 + quad * 8;
    f32x4 acc0 = {}, acc1 = {}, acc2 = {}, acc3 = {};
    #pragma unroll
    for (int kk = 0; kk < 2; ++kk) {
        f16x8 bv = wz[kk];
        f16x8 a0 = *(const f16x8*)(ap + kk * 32);
        f16x8 a1 = *(const f16x8*)(ap + 16384 + kk * 32);
        f16x8 a2 = *(const f16x8*)(ap + 32768 + kk * 32);
        f16x8 a3 = *(const f16x8*)(ap + 49152 + kk * 32);
        acc0 = MFMA16(a0, bv, acc0);
        acc1 = MFMA16(a1, bv, acc1);
        acc2 = MFMA16(a2, bv, acc2);
        acc3 = MFMA16(a3, bv, acc3);
    }
    #pragma unroll
    for (int r = 0; r < 4; ++r) {
        int mb = quad * 4 + r;
        lds[(w * 64 + mb) * 17 + n]      = acc0[r];
        lds[(w * 64 + 16 + mb) * 17 + n] = acc1[r];
        lds[(w * 64 + 32 + mb) * 17 + n] = acc2[r];
        lds[(w * 64 + 48 + mb) * 17 + n] = acc3[r];
    }
    __syncthreads();
    int m = tid >> 3, n0 = (tid & 7) * 2;
    float s0 = 0.f, s1 = 0.f;
    #pragma unroll
    for (int ww = 0; ww < 8; ++ww) {
        const float* p = lds + (ww * 64 + m) * 17 + n0;
        s0 += p[0]; s1 += p[1];
    }
    int e = bb * 16 + n0;
    if (khalf == 0) { s0 += b2[e]; s1 += b2[e + 1]; }
    union { float f[2]; u64 u; } pk;
    pk.f[0] = s0; pk.f[1] = s1;
    bstore8(Z1f + khalf * 32768 + (long)m * 512 + e, pk.u);
}

// ---------------- persistent decoder ----------------
__global__ __launch_bounds__(512, 2) void k_persist(
    const f16* __restrict__ wcat, const float* __restrict__ bsum,
    float* __restrict__ c01, const f16* __restrict__ Xall,
    f16* __restrict__ Orot, f16* __restrict__ H0rot, f16* __restrict__ H1rot,
    const f16* __restrict__ P16, const f16* __restrict__ Q216,
    const f16* __restrict__ w2b, const float* __restrict__ sb,
    const float* __restrict__ b2, float* __restrict__ out,
    float* __restrict__ Z1f, float* __restrict__ Z2p,
    float* __restrict__ Sc, unsigned* __restrict__ sync)
{
    extern __shared__ float smem[];
    float* scr = smem;                    // 8960 floats scratch
    f16* Pl  = (f16*)(smem + 8960);       // 32768 f16
    f16* Q2l = Pl + 32768;                // 16384 f16

    int b = blockIdx.x, tid = threadIdx.x;
    int m = b >> 2, sq = b & 3;
    int wv = tid >> 6, lane = tid & 63, quad = lane >> 4, nn = lane & 15;
    unsigned* cnt = sync + 1024;          // 64 counters, 32-u32 stride

    // -------- prologue: pin weights in VGPRs, P/Q2 slices in LDS --------
    f16x8 w0[8], w1[8];
    {
        int j0 = (nn & 3) * 1024 + b * 4 + (nn >> 2);
        const f16* wp = wcat + (long)j0 * 2048 + wv * 256 + quad * 8;
        #pragma unroll
        for (int kk = 0; kk < 8; ++kk) {
            w0[kk] = *(const f16x8*)(wp + kk * 32);
            w1[kk] = *(const f16x8*)(wp + 8388608 + kk * 32);
        }
    }
    f16x8 wz[2];
    if (b >= 64 && b < 128) {
        int zb = b - 64, bb = zb & 31, kh = zb >> 5;
        int j = bb * 16 + nn;
        const f16* zp = w2b + (long)j * 1024 + kh * 512 + wv * 64 + quad * 8;
        #pragma unroll
        for (int kk = 0; kk < 2; ++kk) wz[kk] = *(const f16x8*)(zp + kk * 32);
    }
    {
        const uint4* gp = (const uint4*)(P16 + ((long)(m * 128 + sq * 32)) * 1024);
        #pragma unroll
        for (int i = 0; i < 8; ++i) ((uint4*)Pl)[i * 512 + tid] = gp[i * 512 + tid];
        const uint4* gq = (const uint4*)(Q216 + ((long)(m * 128 + sq * 32)) * 512);
        #pragma unroll
        for (int i = 0; i < 4; ++i) ((uint4*)Q2l)[i * 512 + tid] = gq[i * 512 + tid];
    }
    __syncthreads();

    unsigned epoch = 0;
    for (int t = 0; t < 64; ++t) {
        int rs0 = t & (ROT - 1), rs1 = (t + 1) & (ROT - 1);
        const f16* Xc = Xall + (long)t * 32768;
        const f16* Oc = Orot + (long)rs0 * 32768;
        const f16* H0c = H0rot + (long)rs0 * 65536;
        f16* H0n = H0rot + (long)rs1 * 65536;
        const f16* H1c = H1rot + (long)rs0 * 65536;
        f16* H1n = H1rot + (long)rs1 * 65536;

        // ---- S1: layer 0, K = [x(512) | o(512) | h0prev(1024)] ----
        {
            const f16* base; int rst;
            if (wv < 2)      { base = Xc + wv * 256;        rst = 512; }
            else if (wv < 4) { base = Oc + (wv - 2) * 256;  rst = 512; }
            else             { base = H0c + (wv - 4) * 256; rst = 1024; }
            lstm_core(base, rst, w0, bsum, c01, H0n, scr, b, tid);
        }
        gsync(sync, ++epoch);

        // ---- S2: layer 1, K = [h0(1024) | h1prev(1024)] ----
        {
            const f16* base = (wv < 4) ? (H0n + wv * 256) : (H1c + (wv - 4) * 256);
            lstm_core(base, 1024, w1, bsum + 4096, c01 + 65536, H1n, scr, b, tid);
        }
        gsync(sync, ++epoch);

        // ---- S3: scores (all blocks) + Z1 halves (blocks 64..127) ----
        {
            f16* h1l = (f16*)scr;
            if (tid < 128)
                ((uint4*)h1l)[tid] = *(const uint4*)(H1n + (long)m * 1024 + tid * 8);
            __syncthreads();
            int sl = tid >> 4, kc = tid & 15;
            const f16* prow = Pl + sl * 1024;
            float a0 = 0.f;
            #pragma unroll
            for (int i = 0; i < 8; ++i) {
                int ch = (i * 16 + kc) * 8;
                f16x8 pv = *(const f16x8*)(prow + ch);
                f16x8 hv = *(const f16x8*)(h1l + ch);
                #pragma unroll
                for (int p2 = 0; p2 < 4; ++p2) {
                    f16x2 pa = { pv[p2 * 2], pv[p2 * 2 + 1] };
                    f16x2 ha = { hv[p2 * 2], hv[p2 * 2 + 1] };
                    a0 = __builtin_amdgcn_fdot2(pa, ha, a0, false);
                }
            }
            #pragma unroll
            for (int off = 8; off; off >>= 1) a0 += __shfl_xor(a0, off, 16);
            if (kc == 0)
                bstore4(Sc + m * 128 + sq * 32 + sl, a0 + sb[m * 128 + sq * 32 + sl]);
            __syncthreads();
            if (b >= 64 && b < 128)
                z1_core(H1n, wz, b2, Z1f, (b - 64) & 31, (b - 64) >> 5, scr, tid);
        }
        gsync(sync, ++epoch);

        // ---- S4: softmax + Z2 partial + winner finish ----
        {
            if (tid < 128) scr[tid] = bload_f32(Sc + m * 128 + tid);
            __syncthreads();
            if (tid < 64) {
                float v = fmaxf(scr[tid], scr[64 + tid]);
                #pragma unroll
                for (int off = 32; off; off >>= 1) v = fmaxf(v, __shfl_down(v, off));
                if (tid == 0) scr[128] = v;
            }
            __syncthreads();
            if (tid < 128) scr[tid] = __expf(scr[tid] - scr[128]);
            __syncthreads();
            if (tid < 64) {
                float v = scr[tid] + scr[64 + tid];
                #pragma unroll
                for (int off = 32; off; off >>= 1) v += __shfl_down(v, off);
                if (tid == 0) scr[129] = 1.f / v;
            }
            __syncthreads();
            float inv = scr[129];
            float zp = 0.f;
            #pragma unroll 8
            for (int jy = 0; jy < 32; ++jy)
                zp += scr[sq * 32 + jy] * (float)Q2l[jy * 512 + tid];
            bstore4(Z2p + ((m * 4 + sq) << 9) + tid, zp * inv);
            asm volatile("s_waitcnt vmcnt(0)" ::: "memory");
            __syncthreads();
            if (tid == 0) {
                unsigned old = __hip_atomic_fetch_add(cnt + m * 32, 1u,
                        __ATOMIC_RELAXED, __HIP_MEMORY_SCOPE_AGENT);
                scr[130] = (old == (unsigned)(4 * t + 3)) ? 1.f : 0.f;
            }
            __syncthreads();
            if (scr[130] != 0.f) {
                float z = bload_f32(Z1f + (m << 9) + tid)
                        + bload_f32(Z1f + 32768 + (m << 9) + tid);
                #pragma unroll
                for (int q = 0; q < 4; ++q)
                    z += bload_f32(Z2p + ((m * 4 + q) << 9) + tid);
                float o = ftanh(z);
                out[((long)m * 64 + t) * 512 + tid] = o;
                f16* ob = (f16*)(scr + 192);
                ob[tid] = (f16)o;
                __syncthreads();
                if (tid < 128) {
                    union { f16 h[4]; u64 u; } pk;
                    #pragma unroll
                    for (int i = 0; i < 4; ++i) pk.h[i] = ob[tid * 4 + i];
                    bstore8(Orot + (long)rs1 * 32768 + m * 512 + tid * 4, pk.u);
                }
            }
        }
        gsync(sync, ++epoch);
    }
}

extern "C" void kernel_launch(void* const* d_in, const int* in_sizes, int n_in,
                              void* d_out, int out_size, void* d_ws, size_t ws_size,
                              hipStream_t stream)
{
    const int*   tgt   = (const int*)d_in[0];
    const float* henc  = (const float*)d_in[1];
    const float* emb   = (const float*)d_in[2];
    const float* oinit = (const float*)d_in[3];
    const float* hinit = (const float*)d_in[4];
    const float* Wih   = (const float*)d_in[5];
    const float* Whh   = (const float*)d_in[6];
    const float* bih   = (const float*)d_in[7];
    const float* bhh   = (const float*)d_in[8];
    const float* W1    = (const float*)d_in[9];
    const float* b1    = (const float*)d_in[10];
    const float* W2    = (const float*)d_in[11];
    const float* b2    = (const float*)d_in[12];
    float* out = (float*)d_out;

    char* ws = (char*)d_ws;
    f16*      wcat  = (f16*)(ws + 0);              // 32 MB
    f16*      P16   = (f16*)(ws + 33554432);       // 16 MB
    f16*      Q216  = (f16*)(ws + 50331648);       //  8 MB
    f16*      h16   = (f16*)(ws + 58720256);       // 16 MB
    f16*      w2b   = (f16*)(ws + 75497472);       //  1 MB
    f16*      w1c   = (f16*)(ws + 76546048);       //  2 MB
    f16*      w2a   = (f16*)(ws + 78643200);       //  1 MB
    f16*      Xall  = (f16*)(ws + 79691776);       //  4 MB
    f16*      H0rot = (f16*)(ws + 83886080);       //  2 MB (16 slots)
    f16*      H1rot = (f16*)(ws + 85983232);       //  2 MB
    f16*      Orot  = (f16*)(ws + 88080384);       //  1 MB
    float*    c01   = (float*)(ws + 89128960);     // 512 KB
    float*    Z1f   = (float*)(ws + 89653248);     // 256 KB (2 halves)
    float*    Z2p   = (float*)(ws + 89915392);     // 512 KB
    float*    Sc    = (float*)(ws + 90439680);     //  32 KB
    float*    bsum  = (float*)(ws + 90472448);     //  32 KB
    float*    sb    = (float*)(ws + 90505216);     //  32 KB
    unsigned* sync  = (unsigned*)(ws + 90537984);  //  12 KB: arr|rel|mst|cnt

    hipLaunchKernelGGL(k_convert, dim3(4096), dim3(256), 0, stream,
                       Wih, Whh, W1, W2, bih, bhh, tgt, emb, henc,
                       wcat, w1c, w2a, w2b, bsum, Xall, h16);
    hipLaunchKernelGGL(k_init, dim3(1164), dim3(256), 0, stream,
                       oinit, hinit, Orot, H0rot, H1rot, c01, sync);
    hipLaunchKernelGGL(k_sb, dim3(32), dim3(256), 0, stream, b1, henc, sb);
    hipLaunchKernelGGL(k_gemm, dim3(128 * 8), dim3(256), 0, stream,
                       h16, w1c, P16, 1024);
    hipLaunchKernelGGL(k_gemm, dim3(128 * 4), dim3(256), 0, stream,
                       h16, w2a, Q216, 512);

    static const unsigned LDS_BYTES = 8960 * 4 + 32768 * 2 + 16384 * 2; // 134144
    hipFuncSetAttribute((const void*)k_persist,
                        hipFuncAttributeMaxDynamicSharedMemorySize, LDS_BYTES);
    void* args[] = { &wcat, &bsum, &c01, &Xall, &Orot, &H0rot, &H1rot, &P16,
                     &Q216, &w2b, &sb, &b2, &out, &Z1f, &Z2p, &Sc, &sync };
    hipLaunchCooperativeKernel((const void*)k_persist, dim3(256), dim3(512),
                               args, LDS_BYTES, stream);
}